// Round 1
// baseline (1967.978 us; speedup 1.0000x reference)
//
#include <hip/hip_runtime.h>
#include <cstddef>
#include <cstdint>

#define N_NODES 100000
#define N_EDGES 3200000
#define D 256

// ---------------- degree histogram ----------------
__global__ __launch_bounds__(256) void hist_kernel(const int* __restrict__ row,
                                                   int* __restrict__ deg) {
    int e = blockIdx.x * 256 + threadIdx.x;
    if (e < N_EDGES) atomicAdd(&deg[row[e]], 1);
}

// ---------------- exclusive scan over degrees (single block, 1024 thr) ----------------
__global__ __launch_bounds__(1024) void scan_kernel(const int* __restrict__ deg,
                                                    int* __restrict__ rowptr,
                                                    int* __restrict__ cursor) {
    __shared__ int waveTot[16];
    __shared__ int waveOff[16];
    __shared__ int s_total;
    __shared__ int s_carry;
    const int tid  = threadIdx.x;
    const int lane = tid & 63;
    const int wv   = tid >> 6;
    if (tid == 0) s_carry = 0;
    __syncthreads();
    for (int base = 0; base < N_NODES; base += 1024) {
        int idx = base + tid;
        int v = (idx < N_NODES) ? deg[idx] : 0;
        int inc = v;
#pragma unroll
        for (int off = 1; off < 64; off <<= 1) {
            int up = __shfl_up(inc, off, 64);
            if (lane >= off) inc += up;
        }
        if (lane == 63) waveTot[wv] = inc;
        __syncthreads();
        if (tid == 0) {
            int run = 0;
#pragma unroll
            for (int w = 0; w < 16; ++w) { waveOff[w] = run; run += waveTot[w]; }
            s_total = run;
        }
        __syncthreads();
        int exc = s_carry + waveOff[wv] + (inc - v);
        if (idx < N_NODES) { rowptr[idx] = exc; cursor[idx] = exc; }
        __syncthreads();
        if (tid == 0) s_carry += s_total;
        __syncthreads();
    }
    if (tid == 0) rowptr[N_NODES] = s_carry;
}

// ---------------- scatter edges into CSR order ----------------
__global__ __launch_bounds__(256) void scatter_kernel(const int* __restrict__ row,
                                                      const int* __restrict__ col,
                                                      const float* __restrict__ val,
                                                      int* __restrict__ cursor,
                                                      int* __restrict__ ccol,
                                                      float* __restrict__ cval) {
    int e = blockIdx.x * 256 + threadIdx.x;
    if (e < N_EDGES) {
        int r = row[e];
        int pos = atomicAdd(&cursor[r], 1);
        ccol[pos] = col[e];
        cval[pos] = val[e];
    }
}

// ---------------- CSR SpMM: one block (256 thr) per node ----------------
#define ECHUNK 128
__global__ __launch_bounds__(256) void spmm_kernel(const int* __restrict__ rowptr,
                                                   const int* __restrict__ ccol,
                                                   const float* __restrict__ cval,
                                                   const float* __restrict__ h,
                                                   float* __restrict__ out) {
    const int i   = blockIdx.x;
    const int tid = threadIdx.x;
    const int start = rowptr[i];
    const int end   = rowptr[i + 1];
    __shared__ int   scol[ECHUNK];
    __shared__ float sval[ECHUNK];
    float acc = 0.f;
    for (int k0 = start; k0 < end; k0 += ECHUNK) {
        const int m = min(ECHUNK, end - k0);
        __syncthreads();
        if (tid < m) { scol[tid] = ccol[k0 + tid]; sval[tid] = cval[k0 + tid]; }
        __syncthreads();
        int k = 0;
        for (; k + 4 <= m; k += 4) {
            float v0 = sval[k], v1 = sval[k + 1], v2 = sval[k + 2], v3 = sval[k + 3];
            float a0 = h[(size_t)scol[k]     * D + tid];
            float a1 = h[(size_t)scol[k + 1] * D + tid];
            float a2 = h[(size_t)scol[k + 2] * D + tid];
            float a3 = h[(size_t)scol[k + 3] * D + tid];
            acc = fmaf(v0, a0, acc);
            acc = fmaf(v1, a1, acc);
            acc = fmaf(v2, a2, acc);
            acc = fmaf(v3, a3, acc);
        }
        for (; k < m; ++k)
            acc = fmaf(sval[k], h[(size_t)scol[k] * D + tid], acc);
    }
    out[(size_t)i * D + tid] = acc;
}

// ---------------- concat-GEMM: out = act([A1|A2] @ W + bias) ----------------
// W is [512][256] row-major; rows 0..255 multiply A1, rows 256..511 multiply A2.
// 64x64 tile per block, 4x4 micro-tile per thread (256 threads).
template <bool RELU>
__global__ __launch_bounds__(256) void gemm_kernel(const float* __restrict__ A1,
                                                   const float* __restrict__ A2,
                                                   const float* __restrict__ W,
                                                   const float* __restrict__ bias,
                                                   float* __restrict__ out) {
    __shared__ float As[16][68];  // [k][m], row stride 68 floats = 16B-aligned
    __shared__ float Bs[16][68];  // [k][j]
    const int tid = threadIdx.x;
    const int tx = tid & 15;   // col group (4 cols each)
    const int ty = tid >> 4;   // row group (4 rows each)
    const int bm = blockIdx.x * 64;
    const int bn = blockIdx.y * 64;
    const int la_k = tid & 15;   // A-load: k index
    const int la_m = tid >> 4;   // A-load: m index base (stride 16)
    const int lb_j = tid & 63;   // B-load: j index
    const int lb_k = tid >> 6;   // B-load: k index base (stride 4)

    float acc[4][4] = {};

    for (int t = 0; t < 32; ++t) {
        const float* __restrict__ A = (t < 16) ? A1 : A2;
        const int k0  = (t & 15) * 16;  // column offset within A (0..240)
        const int wk0 = t * 16;         // row offset within W  (0..496)
        // stage A tile: As[k][m] = A[bm+m][k0+k]
#pragma unroll
        for (int p = 0; p < 4; ++p) {
            int m = la_m + p * 16;
            int r = bm + m;
            if (r > N_NODES - 1) r = N_NODES - 1;  // clamp (stores are guarded)
            As[la_k][m] = A[(size_t)r * D + k0 + la_k];
        }
        // stage B tile: Bs[k][j] = W[wk0+k][bn+j]
#pragma unroll
        for (int p = 0; p < 4; ++p) {
            int k = lb_k + p * 4;
            Bs[k][lb_j] = W[(size_t)(wk0 + k) * D + bn + lb_j];
        }
        __syncthreads();
#pragma unroll
        for (int kk = 0; kk < 16; ++kk) {
            float4 a4 = *reinterpret_cast<const float4*>(&As[kk][ty * 4]);
            float4 b4 = *reinterpret_cast<const float4*>(&Bs[kk][tx * 4]);
            float av[4] = {a4.x, a4.y, a4.z, a4.w};
            float bv[4] = {b4.x, b4.y, b4.z, b4.w};
#pragma unroll
            for (int i2 = 0; i2 < 4; ++i2)
#pragma unroll
                for (int j2 = 0; j2 < 4; ++j2)
                    acc[i2][j2] = fmaf(av[i2], bv[j2], acc[i2][j2]);
        }
        __syncthreads();
    }
    // epilogue: bias + optional relu
#pragma unroll
    for (int i2 = 0; i2 < 4; ++i2) {
        int r = bm + ty * 4 + i2;
        if (r < N_NODES) {
#pragma unroll
            for (int j2 = 0; j2 < 4; ++j2) {
                int c = bn + tx * 4 + j2;
                float v = acc[i2][j2] + bias[c];
                if (RELU) v = fmaxf(v, 0.f);
                out[(size_t)r * D + c] = v;
            }
        }
    }
}

extern "C" void kernel_launch(void* const* d_in, const int* in_sizes, int n_in,
                              void* d_out, int out_size, void* d_ws, size_t ws_size,
                              hipStream_t stream) {
    const float* x     = (const float*)d_in[0];
    const int*   erow  = (const int*)d_in[1];
    const int*   ecol  = (const int*)d_in[2];
    const float* evalv = (const float*)d_in[3];
    const float* W1    = (const float*)d_in[4];
    const float* b1    = (const float*)d_in[5];
    const float* Wout  = (const float*)d_in[6];
    const float* bout  = (const float*)d_in[7];
    float* out = (float*)d_out;

    char* ws = (char*)d_ws;
    size_t off = 0;
    auto alloc = [&](size_t bytes) -> void* {
        void* p = ws + off;
        off += (bytes + 255) & ~(size_t)255;
        return p;
    };
    float* neigh  = (float*)alloc((size_t)N_NODES * D * sizeof(float));   // 102.4 MB
    float* h1     = (float*)alloc((size_t)N_NODES * D * sizeof(float));   // 102.4 MB
    int*   rowptr = (int*)alloc((size_t)(N_NODES + 1) * sizeof(int));
    int*   deg    = (int*)alloc((size_t)N_NODES * sizeof(int));
    int*   cursor = (int*)alloc((size_t)N_NODES * sizeof(int));
    int*   ccol   = (int*)alloc((size_t)N_EDGES * sizeof(int));           // 12.8 MB
    float* cval   = (float*)alloc((size_t)N_EDGES * sizeof(float));       // 12.8 MB

    // 1. build CSR (reused by both SpMM layers)
    hipMemsetAsync(deg, 0, (size_t)N_NODES * sizeof(int), stream);
    hist_kernel<<<(N_EDGES + 255) / 256, 256, 0, stream>>>(erow, deg);
    scan_kernel<<<1, 1024, 0, stream>>>(deg, rowptr, cursor);
    scatter_kernel<<<(N_EDGES + 255) / 256, 256, 0, stream>>>(erow, ecol, evalv,
                                                              cursor, ccol, cval);
    // 2. layer 1: neigh = A @ x ; h1 = relu([x|neigh] @ W1 + b1)
    spmm_kernel<<<N_NODES, 256, 0, stream>>>(rowptr, ccol, cval, x, neigh);
    dim3 ggrid((N_NODES + 63) / 64, 4);
    gemm_kernel<true><<<ggrid, 256, 0, stream>>>(x, neigh, W1, b1, h1);
    // 3. layer 2: neigh2 = A @ h1 ; out = [h1|neigh2] @ Wout + bout
    spmm_kernel<<<N_NODES, 256, 0, stream>>>(rowptr, ccol, cval, h1, neigh);
    gemm_kernel<false><<<ggrid, 256, 0, stream>>>(h1, neigh, Wout, bout, out);
}